// Round 5
// baseline (68.571 us; speedup 1.0000x reference)
//
#include <hip/hip_runtime.h>

// Truncated path signature, trunc=4, D=8, B=128, S=512.
// Phase 1 (sig_chunk): 128 batches x 8 chunks x 64 steps, 512-thr blocks.
//   dx computed in-kernel into LDS. Per step, the wave-uniform dx ROW is pulled
//   from VGPR-resident data via v_readlane (SGPR operands feed the FMAs) --
//   nothing on the LDS pipe except the two per-lane picks db, dc (b32 bcast).
//   Barrier-free Chen recurrence after the single staging barrier.
// Phase 2 (sig_combine): 128 blocks fold the 8 chunk signatures (Chen product).
// Thread digits: aa=tid>>6 (== wave id), bb=(tid>>3)&7, cc=tid&7.

constexpr int Bc = 128, Sc = 512, Tc = 511;
constexpr int NCH = 8, CH = 64;
constexpr int SIGSZ = 8 + 64 + 512 + 4096;        // 4680 floats

__device__ __forceinline__ float rlane(float v, int lane) {
    return __int_as_float(__builtin_amdgcn_readlane(__float_as_int(v), lane));
}

// ---------------- Phase 1: per-chunk signature ----------------
__global__ __launch_bounds__(512)
void sig_chunk(const float* __restrict__ path, float* __restrict__ ws) {
    const int blk = blockIdx.x;
    const int b   = blk >> 3;
    const int c   = blk & 7;
    const int tid = threadIdx.x;
    const int t0  = c * CH;

    __shared__ float dxs[CH * 8];                 // 2 KiB
    {
        const float* p = path + (((size_t)b * Sc + t0) << 3);
        float v = 0.f;
        if (t0 * 8 + tid < Tc * 8) v = p[tid + 8] - p[tid];   // row 511 -> 0 (identity)
        dxs[tid] = v;
    }
    __syncthreads();                              // only barrier

    // rv[k]: lane l holds dx[8k + (l>>3)][l&7]  (stride-1 LDS reads, conflict-free)
    const int lane = tid & 63;
    float rv[8];
#pragma unroll
    for (int k = 0; k < 8; ++k) rv[k] = dxs[64 * k + lane];

    const int bb = (tid >> 3) & 7, cc = tid & 7;
    const int aaU = __builtin_amdgcn_readfirstlane(tid) >> 6;  // wave id, uniform

    float acc4[8] = {0.f, 0.f, 0.f, 0.f, 0.f, 0.f, 0.f, 0.f};
    float acc3 = 0.f, s2ab = 0.f, acc2 = 0.f;
    float s1a = 0.f, s1b = 0.f, s1c = 0.f;

#pragma unroll
    for (int t = 0; t < CH; ++t) {
        const int k  = t >> 3;                    // compile-time (full unroll)
        const int lb = (t & 7) << 3;

        float da = rlane(rv[k], lb + aaU);        // SGPR
        float db = dxs[t * 8 + bb];               // LDS b32 broadcast
        float dc = dxs[t * 8 + cc];               // LDS b32 broadcast

        float e = db * dc;
        float m = s2ab * dc;
        float v = fmaf(s1a, 1.f / 6.f, da * (1.f / 24.f));
        float K = fmaf(0.5f, m, acc3);
        K = fmaf(e, v, K);

        float r0 = rlane(rv[k], lb + 0);
        float r1 = rlane(rv[k], lb + 1);
        float r2 = rlane(rv[k], lb + 2);
        float r3 = rlane(rv[k], lb + 3);
        float r4 = rlane(rv[k], lb + 4);
        float r5 = rlane(rv[k], lb + 5);
        float r6 = rlane(rv[k], lb + 6);
        float r7 = rlane(rv[k], lb + 7);

        acc4[0] = fmaf(r0, K, acc4[0]);
        acc4[1] = fmaf(r1, K, acc4[1]);
        acc4[2] = fmaf(r2, K, acc4[2]);
        acc4[3] = fmaf(r3, K, acc4[3]);
        acc4[4] = fmaf(r4, K, acc4[4]);
        acc4[5] = fmaf(r5, K, acc4[5]);
        acc4[6] = fmaf(r6, K, acc4[6]);
        acc4[7] = fmaf(r7, K, acc4[7]);

        float w = fmaf(0.5f, s1a, da * (1.f / 6.f));
        acc3 = acc3 + m;
        acc3 = fmaf(e, w, acc3);

        acc2 = fmaf(s1b, dc, fmaf(0.5f, e, acc2));
        s2ab = fmaf(s1a, db, fmaf(0.5f * da, db, s2ab));
        s1a += da; s1b += db; s1c += dc;
    }

    float* o = ws + (size_t)blk * SIGSZ;
    if (tid < 8)  o[tid] = s1c;
    if (tid < 64) o[8 + tid] = acc2;
    o[72 + tid] = acc3;
    *(float4*)(o + 584 + 8 * tid)     = make_float4(acc4[0], acc4[1], acc4[2], acc4[3]);
    *(float4*)(o + 584 + 8 * tid + 4) = make_float4(acc4[4], acc4[5], acc4[6], acc4[7]);
}

// ---------------- Phase 2: fold chunk signatures ----------------
__global__ __launch_bounds__(512)
void sig_combine(const float* __restrict__ ws, float* __restrict__ out) {
    const int b = blockIdx.x, tid = threadIdx.x;
    const int aa = tid >> 6, bb = (tid >> 3) & 7, cc = tid & 7;

    float x4[8] = {0.f, 0.f, 0.f, 0.f, 0.f, 0.f, 0.f, 0.f};
    float x3 = 0.f, x2ab = 0.f, x2own = 0.f;
    float x1a = 0.f, x1b = 0.f, x1c = 0.f;

#pragma unroll 2
    for (int c = 0; c < NCH; ++c) {
        const float* y = ws + ((size_t)(b * NCH + c)) * SIGSZ;

        float y1a = y[aa], y1b = y[bb], y1c = y[cc];
        float y2ab = y[8 + 8 * aa + bb];
        float y2bc = y[8 + 8 * bb + cc];
        float4 y1lo = *(const float4*)y;
        float4 y1hi = *(const float4*)(y + 4);
        const float* y2r = y + 8 + 8 * cc;
        float4 y2lo = *(const float4*)y2r;
        float4 y2hi = *(const float4*)(y2r + 4);
        const float* y3r = y + 72 + 8 * (tid & 63);
        float4 y3lo = *(const float4*)y3r;
        float4 y3hi = *(const float4*)(y3r + 4);
        float y3own = y[72 + tid];
        const float* y4r = y + 584 + 8 * tid;
        float4 y4lo = *(const float4*)y4r;
        float4 y4hi = *(const float4*)(y4r + 4);

        x4[0] = x4[0] + x3 * y1lo.x + x2ab * y2lo.x + x1a * y3lo.x + y4lo.x;
        x4[1] = x4[1] + x3 * y1lo.y + x2ab * y2lo.y + x1a * y3lo.y + y4lo.y;
        x4[2] = x4[2] + x3 * y1lo.z + x2ab * y2lo.z + x1a * y3lo.z + y4lo.z;
        x4[3] = x4[3] + x3 * y1lo.w + x2ab * y2lo.w + x1a * y3lo.w + y4lo.w;
        x4[4] = x4[4] + x3 * y1hi.x + x2ab * y2hi.x + x1a * y3hi.x + y4hi.x;
        x4[5] = x4[5] + x3 * y1hi.y + x2ab * y2hi.y + x1a * y3hi.y + y4hi.y;
        x4[6] = x4[6] + x3 * y1hi.z + x2ab * y2hi.z + x1a * y3hi.z + y4hi.z;
        x4[7] = x4[7] + x3 * y1hi.w + x2ab * y2hi.w + x1a * y3hi.w + y4hi.w;

        x3 = x3 + x2ab * y1c + x1a * y2bc + y3own;
        x2ab  = x2ab  + x1a * y1b + y2ab;
        x2own = x2own + x1b * y1c + y2bc;
        x1a += y1a; x1b += y1b; x1c += y1c;
    }

    float* o = out + (size_t)b * SIGSZ;
    if (tid < 8)  o[tid] = x1c;
    if (tid < 64) o[8 + tid] = x2own;
    o[72 + tid] = x3;
    *(float4*)(o + 584 + 8 * tid)     = make_float4(x4[0], x4[1], x4[2], x4[3]);
    *(float4*)(o + 584 + 8 * tid + 4) = make_float4(x4[4], x4[5], x4[6], x4[7]);
}

// ---------------- Fallback (single-kernel, used if ws too small) ----------------
__global__ __launch_bounds__(512)
void sig_fallback(const float* __restrict__ path, float* __restrict__ out) {
    const int b = blockIdx.x, tid = threadIdx.x;
    __shared__ float dxAll[Tc * 8];
    const float* prow = path + (size_t)b * Sc * 8;
    for (int n = tid; n < Tc * 8; n += 512) dxAll[n] = prow[n + 8] - prow[n];
    __syncthreads();

    const int aa = tid >> 6, bb = (tid >> 3) & 7, cc = tid & 7;
    float acc4[8] = {0.f, 0.f, 0.f, 0.f, 0.f, 0.f, 0.f, 0.f};
    float acc3 = 0.f, s2ab = 0.f, acc2 = 0.f, s1a = 0.f, s1b = 0.f, s1c = 0.f;
    for (int t = 0; t < Tc; ++t) {
        const float* r = &dxAll[t * 8];
        float4 lo = *(const float4*)r;
        float4 hi = *(const float4*)(r + 4);
        float da = r[aa], db = r[bb], dc = r[cc];
        float e = db * dc;
        float K = acc3 + s2ab * (0.5f * dc) + e * fmaf(s1a, 1.f / 6.f, da * (1.f / 24.f));
        acc4[0] = fmaf(lo.x, K, acc4[0]);
        acc4[1] = fmaf(lo.y, K, acc4[1]);
        acc4[2] = fmaf(lo.z, K, acc4[2]);
        acc4[3] = fmaf(lo.w, K, acc4[3]);
        acc4[4] = fmaf(hi.x, K, acc4[4]);
        acc4[5] = fmaf(hi.y, K, acc4[5]);
        acc4[6] = fmaf(hi.z, K, acc4[6]);
        acc4[7] = fmaf(hi.w, K, acc4[7]);
        acc3 = acc3 + s2ab * dc + e * fmaf(0.5f, s1a, da * (1.f / 6.f));
        acc2 = fmaf(s1b, dc, fmaf(0.5f, e, acc2));
        s2ab = fmaf(s1a, db, fmaf(0.5f * da, db, s2ab));
        s1a += da; s1b += db; s1c += dc;
    }
    float* o = out + (size_t)b * SIGSZ;
    if (tid < 8)  o[tid] = s1c;
    if (tid < 64) o[8 + tid] = acc2;
    o[72 + tid] = acc3;
    *(float4*)(o + 584 + 8 * tid)     = make_float4(acc4[0], acc4[1], acc4[2], acc4[3]);
    *(float4*)(o + 584 + 8 * tid + 4) = make_float4(acc4[4], acc4[5], acc4[6], acc4[7]);
}

extern "C" void kernel_launch(void* const* d_in, const int* in_sizes, int n_in,
                              void* d_out, int out_size, void* d_ws, size_t ws_size,
                              hipStream_t stream) {
    const float* path = (const float*)d_in[0];
    float* out = (float*)d_out;
    const size_t need = (size_t)Bc * NCH * SIGSZ * sizeof(float);   // ~19.2 MB
    if (ws_size >= need) {
        float* ws = (float*)d_ws;
        sig_chunk  <<<dim3(Bc * NCH), dim3(512), 0, stream>>>(path, ws);
        sig_combine<<<dim3(Bc), dim3(512), 0, stream>>>(ws, out);
    } else {
        sig_fallback<<<dim3(Bc), dim3(512), 0, stream>>>(path, out);
    }
}

// Round 6
// 33.932 us; speedup vs baseline: 2.0208x; 2.0208x over previous
//
#include <hip/hip_runtime.h>

// Truncated path signature, trunc=4, D=8, B=128, S=512.
// Phase 1 (sig_chunk): 1024 blocks (128 batches x 8 chunks of 64 steps),
//   128 threads (2 waves). Lane = (a,b) digits; wave id selects c-range
//   {4h..4h+3} via template<CB> (compile-time register indices for dc).
//   Lane state: acc4[4][8] (level-4 elems (a,b,c,d)), acc3[4], s2ab, s1a.
//   Level-1/2 outputs come free from s1a / s2ab of wave-0 lanes.
//   Per block-step LDS: 2 waves x (2x ds_read_b128 row + 2x b32 picks) -- the
//   round-2 structure cost 331 cy/block-step; this is 71 cy.
// Phase 2 (sig_combine): 128 blocks fold the 8 chunk signatures (unchanged).

constexpr int Bc = 128, Sc = 512, Tc = 511;
constexpr int NCH = 8, CH = 64;
constexpr int SIGSZ = 8 + 64 + 512 + 4096;        // 4680 floats

// ---------------- Phase 1 inner loop (CB = 4*waveid, compile-time) ----------------
template <int CB>
__device__ __forceinline__ void run_loop(
    const float* __restrict__ dxs, int a, int bcoord,
    float acc4[4][8], float acc3[4], float& s2ab, float& s1a)
{
#pragma unroll 4
    for (int t = 0; t < CH; ++t) {
        const float* rp = &dxs[t * 8];
        float4 lo = *(const float4*)rp;           // broadcast b128
        float4 hi = *(const float4*)(rp + 4);     // broadcast b128
        float r[8] = {lo.x, lo.y, lo.z, lo.w, hi.x, hi.y, hi.z, hi.w};
        float da = rp[a];                         // LDS b32, conflict-free
        float db = rp[bcoord];                    // LDS b32, conflict-free

        float v = fmaf(s1a, 1.f / 6.f, da * (1.f / 24.f));
        float w = fmaf(0.5f, s1a, da * (1.f / 6.f));

#pragma unroll
        for (int j = 0; j < 4; ++j) {
            float dc = r[CB + j];                 // compile-time index
            float e = db * dc;
            float m = s2ab * dc;
            float K = fmaf(0.5f, m, acc3[j]);
            K = fmaf(e, v, K);
#pragma unroll
            for (int d = 0; d < 8; ++d)
                acc4[j][d] = fmaf(r[d], K, acc4[j][d]);
            acc3[j] += m;
            acc3[j] = fmaf(e, w, acc3[j]);
        }
        s2ab = fmaf(s1a, db, fmaf(0.5f * da, db, s2ab));
        s1a += da;
    }
}

// ---------------- Phase 1: per-chunk signature ----------------
__global__ __launch_bounds__(128)
void sig_chunk(const float* __restrict__ path, float* __restrict__ ws) {
    const int blk = blockIdx.x;
    const int b   = blk >> 3;
    const int c   = blk & 7;
    const int tid = threadIdx.x;
    const int t0  = c * CH;

    __shared__ float dxs[CH * 8];                 // 2 KiB
    {
        const float* p = path + (((size_t)b * Sc + t0) << 3);
#pragma unroll
        for (int i = tid; i < CH * 8; i += 128) {
            float v = 0.f;
            if (t0 * 8 + i < Tc * 8) v = p[i + 8] - p[i];   // pad row 511 -> 0
            dxs[i] = v;
        }
    }
    __syncthreads();                              // only barrier

    const int half   = tid >> 6;                  // wave id (0/1), uniform per wave
    const int a      = (tid >> 3) & 7;
    const int bcoord = tid & 7;
    const int k      = tid & 63;                  // (a,b) pair index

    float acc4[4][8];
#pragma unroll
    for (int j = 0; j < 4; ++j)
#pragma unroll
        for (int d = 0; d < 8; ++d) acc4[j][d] = 0.f;
    float acc3[4] = {0.f, 0.f, 0.f, 0.f};
    float s2ab = 0.f, s1a = 0.f;

    if (half == 0) run_loop<0>(dxs, a, bcoord, acc4, acc3, s2ab, s1a);
    else           run_loop<4>(dxs, a, bcoord, acc4, acc3, s2ab, s1a);

    // ---- write signature: [s1(8) | s2(64) | s3(512) | s4(4096)] ----
    float* o = ws + (size_t)blk * SIGSZ;
    if (half == 0) {
        if (bcoord == 0) o[a] = s1a;              // level-1 elem a
        o[8 + k] = s2ab;                          // level-2 elem (a,b)
    }
    // level-3 elems (a,b, 4*half + j): contiguous float4
    *(float4*)(o + 72 + k * 8 + half * 4) = make_float4(acc3[0], acc3[1], acc3[2], acc3[3]);
    // level-4 elems (a,b,c,d)
#pragma unroll
    for (int j = 0; j < 4; ++j) {
        float* p4 = o + 584 + k * 64 + (half * 4 + j) * 8;
        *(float4*)(p4)     = make_float4(acc4[j][0], acc4[j][1], acc4[j][2], acc4[j][3]);
        *(float4*)(p4 + 4) = make_float4(acc4[j][4], acc4[j][5], acc4[j][6], acc4[j][7]);
    }
}

// ---------------- Phase 2: fold chunk signatures ----------------
__global__ __launch_bounds__(512)
void sig_combine(const float* __restrict__ ws, float* __restrict__ out) {
    const int b = blockIdx.x, tid = threadIdx.x;
    const int aa = tid >> 6, bb = (tid >> 3) & 7, cc = tid & 7;

    float x4[8] = {0.f, 0.f, 0.f, 0.f, 0.f, 0.f, 0.f, 0.f};
    float x3 = 0.f, x2ab = 0.f, x2own = 0.f;
    float x1a = 0.f, x1b = 0.f, x1c = 0.f;

#pragma unroll 2
    for (int c = 0; c < NCH; ++c) {
        const float* y = ws + ((size_t)(b * NCH + c)) * SIGSZ;

        float y1a = y[aa], y1b = y[bb], y1c = y[cc];
        float y2ab = y[8 + 8 * aa + bb];
        float y2bc = y[8 + 8 * bb + cc];
        float4 y1lo = *(const float4*)y;
        float4 y1hi = *(const float4*)(y + 4);
        const float* y2r = y + 8 + 8 * cc;
        float4 y2lo = *(const float4*)y2r;
        float4 y2hi = *(const float4*)(y2r + 4);
        const float* y3r = y + 72 + 8 * (tid & 63);
        float4 y3lo = *(const float4*)y3r;
        float4 y3hi = *(const float4*)(y3r + 4);
        float y3own = y[72 + tid];
        const float* y4r = y + 584 + 8 * tid;
        float4 y4lo = *(const float4*)y4r;
        float4 y4hi = *(const float4*)(y4r + 4);

        x4[0] = x4[0] + x3 * y1lo.x + x2ab * y2lo.x + x1a * y3lo.x + y4lo.x;
        x4[1] = x4[1] + x3 * y1lo.y + x2ab * y2lo.y + x1a * y3lo.y + y4lo.y;
        x4[2] = x4[2] + x3 * y1lo.z + x2ab * y2lo.z + x1a * y3lo.z + y4lo.z;
        x4[3] = x4[3] + x3 * y1lo.w + x2ab * y2lo.w + x1a * y3lo.w + y4lo.w;
        x4[4] = x4[4] + x3 * y1hi.x + x2ab * y2hi.x + x1a * y3hi.x + y4hi.x;
        x4[5] = x4[5] + x3 * y1hi.y + x2ab * y2hi.y + x1a * y3hi.y + y4hi.y;
        x4[6] = x4[6] + x3 * y1hi.z + x2ab * y2hi.z + x1a * y3hi.z + y4hi.z;
        x4[7] = x4[7] + x3 * y1hi.w + x2ab * y2hi.w + x1a * y3hi.w + y4hi.w;

        x3 = x3 + x2ab * y1c + x1a * y2bc + y3own;
        x2ab  = x2ab  + x1a * y1b + y2ab;
        x2own = x2own + x1b * y1c + y2bc;
        x1a += y1a; x1b += y1b; x1c += y1c;
    }

    float* o = out + (size_t)b * SIGSZ;
    if (tid < 8)  o[tid] = x1c;
    if (tid < 64) o[8 + tid] = x2own;
    o[72 + tid] = x3;
    *(float4*)(o + 584 + 8 * tid)     = make_float4(x4[0], x4[1], x4[2], x4[3]);
    *(float4*)(o + 584 + 8 * tid + 4) = make_float4(x4[4], x4[5], x4[6], x4[7]);
}

// ---------------- Fallback (single-kernel, used if ws too small) ----------------
__global__ __launch_bounds__(512)
void sig_fallback(const float* __restrict__ path, float* __restrict__ out) {
    const int b = blockIdx.x, tid = threadIdx.x;
    __shared__ float dxAll[Tc * 8];
    const float* prow = path + (size_t)b * Sc * 8;
    for (int n = tid; n < Tc * 8; n += 512) dxAll[n] = prow[n + 8] - prow[n];
    __syncthreads();

    const int aa = tid >> 6, bb = (tid >> 3) & 7, cc = tid & 7;
    float acc4[8] = {0.f, 0.f, 0.f, 0.f, 0.f, 0.f, 0.f, 0.f};
    float acc3 = 0.f, s2ab = 0.f, acc2 = 0.f, s1a = 0.f, s1b = 0.f, s1c = 0.f;
    for (int t = 0; t < Tc; ++t) {
        const float* r = &dxAll[t * 8];
        float4 lo = *(const float4*)r;
        float4 hi = *(const float4*)(r + 4);
        float da = r[aa], db = r[bb], dc = r[cc];
        float e = db * dc;
        float K = acc3 + s2ab * (0.5f * dc) + e * fmaf(s1a, 1.f / 6.f, da * (1.f / 24.f));
        acc4[0] = fmaf(lo.x, K, acc4[0]);
        acc4[1] = fmaf(lo.y, K, acc4[1]);
        acc4[2] = fmaf(lo.z, K, acc4[2]);
        acc4[3] = fmaf(lo.w, K, acc4[3]);
        acc4[4] = fmaf(hi.x, K, acc4[4]);
        acc4[5] = fmaf(hi.y, K, acc4[5]);
        acc4[6] = fmaf(hi.z, K, acc4[6]);
        acc4[7] = fmaf(hi.w, K, acc4[7]);
        acc3 = acc3 + s2ab * dc + e * fmaf(0.5f, s1a, da * (1.f / 6.f));
        acc2 = fmaf(s1b, dc, fmaf(0.5f, e, acc2));
        s2ab = fmaf(s1a, db, fmaf(0.5f * da, db, s2ab));
        s1a += da; s1b += db; s1c += dc;
    }
    float* o = out + (size_t)b * SIGSZ;
    if (tid < 8)  o[tid] = s1c;
    if (tid < 64) o[8 + tid] = acc2;
    o[72 + tid] = acc3;
    *(float4*)(o + 584 + 8 * tid)     = make_float4(acc4[0], acc4[1], acc4[2], acc4[3]);
    *(float4*)(o + 584 + 8 * tid + 4) = make_float4(acc4[4], acc4[5], acc4[6], acc4[7]);
}

extern "C" void kernel_launch(void* const* d_in, const int* in_sizes, int n_in,
                              void* d_out, int out_size, void* d_ws, size_t ws_size,
                              hipStream_t stream) {
    const float* path = (const float*)d_in[0];
    float* out = (float*)d_out;
    const size_t need = (size_t)Bc * NCH * SIGSZ * sizeof(float);   // ~19.2 MB
    if (ws_size >= need) {
        float* ws = (float*)d_ws;
        sig_chunk  <<<dim3(Bc * NCH), dim3(128), 0, stream>>>(path, ws);
        sig_combine<<<dim3(Bc), dim3(512), 0, stream>>>(ws, out);
    } else {
        sig_fallback<<<dim3(Bc), dim3(512), 0, stream>>>(path, out);
    }
}